// Round 1
// baseline (46.770 us; speedup 1.0000x reference)
//
#include <hip/hip_runtime.h>
#include <hip/hip_bf16.h>

typedef __bf16 bf16x4 __attribute__((ext_vector_type(4)));
typedef __bf16 bf16x8 __attribute__((ext_vector_type(8)));
typedef float f32x4 __attribute__((ext_vector_type(4)));

#define B_    8
#define NTOK  4096
#define CIN   512
#define COUT  512
#define SDIM  512
#define EPSF  1e-8f

// ---------------------------------------------------------------------------
// K1: m[b][i] = style[b,:] . mod_w[i,:] + mod_b[i] + 1    (one wave per output)
// ---------------------------------------------------------------------------
__global__ __launch_bounds__(256) void k_stylefc(
    const float* __restrict__ style, const float* __restrict__ mod_w,
    const float* __restrict__ mod_b, float* __restrict__ m_out) {
  int gw   = (blockIdx.x * 256 + threadIdx.x) >> 6;  // 0..4095
  int lane = threadIdx.x & 63;
  int b = gw >> 9;
  int i = gw & 511;
  const float* srow = style + (size_t)b * SDIM;
  const float* wrow = mod_w + (size_t)i * SDIM;
  float acc = 0.f;
#pragma unroll
  for (int k = 0; k < SDIM; k += 64) acc += srow[k + lane] * wrow[k + lane];
#pragma unroll
  for (int off = 32; off; off >>= 1) acc += __shfl_xor(acc, off, 64);
  if (lane == 0) m_out[b * CIN + i] = acc + mod_b[i] + 1.0f;
}

// ---------------------------------------------------------------------------
// K2: per output-channel o:
//   demod[b][o] = rsqrt( sum_i (weight[i][o]*m[b][i])^2 + eps )  for all 8 b
//   wT[o][i]    = bf16(weight[i][o])   (transposed for GEMM B staging)
// one block (256 thr) per o
// ---------------------------------------------------------------------------
__global__ __launch_bounds__(256) void k_wprep(
    const float* __restrict__ weight, const float* __restrict__ m_buf,
    __bf16* __restrict__ wT, float* __restrict__ demod) {
  int o = blockIdx.x;
  int tid = threadIdx.x;
  int wid = tid >> 6, lane = tid & 63;
  float acc[B_] = {0.f, 0.f, 0.f, 0.f, 0.f, 0.f, 0.f, 0.f};
#pragma unroll
  for (int rep = 0; rep < 2; ++rep) {
    int i = tid + rep * 256;
    float w = weight[(size_t)i * COUT + o];
    wT[(size_t)o * CIN + i] = (__bf16)w;
#pragma unroll
    for (int b = 0; b < B_; ++b) {
      float wm = w * m_buf[b * CIN + i];
      acc[b] += wm * wm;
    }
  }
  __shared__ float red[4][B_];
#pragma unroll
  for (int b = 0; b < B_; ++b) {
    float v = acc[b];
#pragma unroll
    for (int off = 32; off; off >>= 1) v += __shfl_xor(v, off, 64);
    if (lane == 0) red[wid][b] = v;
  }
  __syncthreads();
  if (tid < B_) {
    float s = red[0][tid] + red[1][tid] + red[2][tid] + red[3][tid];
    demod[tid * COUT + o] = rsqrtf(s + EPSF);
  }
}

// ---------------------------------------------------------------------------
// K3: out[b, t, o] = demod[b][o] * sum_i (x[b,t,i]*m[b][i]) * wT[o][i]
// 128x128 tile, BK=32, 256 thr (4 waves, 2x2), mfma_f32_16x16x32_bf16.
// A reg-staged (f32 load -> *m -> bf16 cvt -> swizzled LDS), B reg-staged.
// LDS XOR swizzle: chunk' = chunk ^ ((row>>1)&3)  -> conflict-free b128 reads.
// XCD-aware bid remap: 4 N-blocks of one x-panel land on the same XCD.
// ---------------------------------------------------------------------------
__global__ __launch_bounds__(256, 2) void k_gemm(
    const float* __restrict__ x, const __bf16* __restrict__ wT,
    const float* __restrict__ m_buf, const float* __restrict__ demod,
    float* __restrict__ out) {
  // decode: 1024 blocks = 8 xcd * 32 panels * 4 nb
  int bid  = blockIdx.x;
  int xcd  = bid & 7;
  int slot = bid >> 3;            // 0..127
  int panel = xcd * 32 + (slot >> 2);  // 0..255  (b, mb)
  int nb   = slot & 3;
  int b    = panel >> 5;          // 0..7
  int mb   = panel & 31;          // 0..31

  __shared__ uint4 lds_u4[1024];  // 16 KiB: A[0..8191], B[8192..16383]
  char* lds = (char*)lds_u4;

  int tid  = threadIdx.x;
  int wid  = tid >> 6, lane = tid & 63;
  int wr   = wid >> 1, wc = wid & 1;

  f32x4 acc[4][4] = {};

  const float*  xbase = x + ((size_t)b * NTOK + (size_t)mb * 128) * CIN;
  const float*  mrow  = m_buf + b * CIN;

  // staging maps
  int arow = tid >> 3, aseg = tid & 7;   // A: 32 rows/pass, seg = 4 f32
  int brow = tid >> 2, bchk = tid & 3;   // B: 64 rows/pass, chunk = 8 bf16

  for (int k0 = 0; k0 < CIN; k0 += 32) {
    // ---- stage A (x * m -> bf16, swizzled) ----
    float4 mv = *(const float4*)(mrow + k0 + aseg * 4);
#pragma unroll
    for (int p = 0; p < 4; ++p) {
      int r = arow + p * 32;
      float4 xv = *(const float4*)(xbase + (size_t)r * CIN + k0 + aseg * 4);
      bf16x4 hv;
      hv[0] = (__bf16)(xv.x * mv.x);
      hv[1] = (__bf16)(xv.y * mv.y);
      hv[2] = (__bf16)(xv.z * mv.z);
      hv[3] = (__bf16)(xv.w * mv.w);
      int chunk = aseg >> 1;
      int sw = chunk ^ ((r >> 1) & 3);
      *(bf16x4*)(lds + r * 64 + sw * 16 + (aseg & 1) * 8) = hv;
    }
    // ---- stage B (wT bf16, swizzled) ----
#pragma unroll
    for (int p = 0; p < 2; ++p) {
      int r = brow + p * 64;              // col o within tile
      int o = nb * 128 + r;
      uint4 v = *(const uint4*)(wT + (size_t)o * CIN + k0 + bchk * 8);
      int sw = bchk ^ ((r >> 1) & 3);
      *(uint4*)(lds + 8192 + r * 64 + sw * 16) = v;
    }
    __syncthreads();

    // ---- fragments + MFMA ----
    bf16x8 af[4], bfr[4];
#pragma unroll
    for (int mm = 0; mm < 4; ++mm) {
      int r = wr * 64 + mm * 16 + (lane & 15);
      int sw = (lane >> 4) ^ ((r >> 1) & 3);
      af[mm] = *(const bf16x8*)(lds + r * 64 + sw * 16);
    }
#pragma unroll
    for (int nn = 0; nn < 4; ++nn) {
      int r = wc * 64 + nn * 16 + (lane & 15);
      int sw = (lane >> 4) ^ ((r >> 1) & 3);
      bfr[nn] = *(const bf16x8*)(lds + 8192 + r * 64 + sw * 16);
    }
#pragma unroll
    for (int mm = 0; mm < 4; ++mm)
#pragma unroll
      for (int nn = 0; nn < 4; ++nn)
        acc[mm][nn] = __builtin_amdgcn_mfma_f32_16x16x32_bf16(
            af[mm], bfr[nn], acc[mm][nn], 0, 0, 0);
    __syncthreads();
  }

  // ---- epilogue: scale by demod[b][col], write f32 ----
  float* obase = out + ((size_t)b * NTOK + (size_t)mb * 128) * COUT + nb * 128;
  const float* drow = demod + b * COUT + nb * 128;
#pragma unroll
  for (int nn = 0; nn < 4; ++nn) {
    int col = wc * 64 + nn * 16 + (lane & 15);
    float d = drow[col];
#pragma unroll
    for (int mm = 0; mm < 4; ++mm) {
      int r0 = wr * 64 + mm * 16 + (lane >> 4) * 4;
#pragma unroll
      for (int j = 0; j < 4; ++j)
        obase[(size_t)(r0 + j) * COUT + col] = acc[mm][nn][j] * d;
    }
  }
}

// ---------------------------------------------------------------------------
extern "C" void kernel_launch(void* const* d_in, const int* in_sizes, int n_in,
                              void* d_out, int out_size, void* d_ws, size_t ws_size,
                              hipStream_t stream) {
  const float* x      = (const float*)d_in[0];  // (8,4096,512)
  const float* style  = (const float*)d_in[1];  // (8,512)
  const float* weight = (const float*)d_in[2];  // (1,512,512)
  const float* mod_w  = (const float*)d_in[3];  // (512,512)
  const float* mod_b  = (const float*)d_in[4];  // (512,)
  float* out = (float*)d_out;

  // ws layout: m[8*512] f32 | demod[8*512] f32 | wT[512*512] bf16  (~544 KiB)
  float*  m_buf = (float*)d_ws;
  float*  demod = m_buf + B_ * CIN;
  __bf16* wT    = (__bf16*)((char*)d_ws + 2 * B_ * CIN * sizeof(float));

  k_stylefc<<<dim3((B_ * CIN) / 4), dim3(256), 0, stream>>>(style, mod_w, mod_b, m_buf);
  k_wprep<<<dim3(COUT), dim3(256), 0, stream>>>(weight, m_buf, wT, demod);
  k_gemm<<<dim3(8 * 32 * 4), dim3(256), 0, stream>>>(x, wT, m_buf, demod, out);
}